// Round 10
// baseline (32.052 us; speedup 1.0000x reference)
//
#include <hip/hip_runtime.h>
#include <hip/hip_bf16.h>

#define NVIS 16384
#define EMB 128
#define HID 64
#define MED 153
#define K1 384
#define VPB 16
#define NTHR 512
#define NBLK (NVIS / VPB)    // 1024 blocks x 512 thr
#define CAPT 1536            // combined staged-code capacity per block

// ---- d_ws layout (16B aligned) ----
#define W2F_OFF  0u                         // 10*2*64 frags * 16B = 20480
#define OFFS_OFF 20480u                     // 3 * 16388 * 4 = 196656
#define OFFS_STRIDE 16388
#define TW_OFF   (20480u + 196656u)         // 217136; 3653 rows * 128 B = 467584
#define WS_NEED  (217136u + 467584u)        // 684720

#define ROWS_D 2000
#define ROWS_P 1500
#define ROWS_M 153
#define TBASE_D 0
#define TBASE_P 2000
#define TBASE_M 3500

#define TWB_D 125            // 16 rows/block
#define TWB_P 94
#define TWB_M 10
#define TWB_ALL (TWB_D + TWB_P + TWB_M)      // 229
#define NW2F 1280

typedef float f32x4 __attribute__((ext_vector_type(4)));
typedef short s16x8 __attribute__((ext_vector_type(8)));
typedef unsigned int u32;
typedef unsigned int u32x4 __attribute__((ext_vector_type(4)));

__device__ __forceinline__ unsigned short f2bf(float f) {
  union { float f; unsigned u; } v; v.f = f;
  unsigned r = v.u + 0x7FFFu + ((v.u >> 16) & 1u);   // round-to-nearest-even
  return (unsigned short)(r >> 16);
}

// unpack 8 bf16 from u32x4, masked-fma into A[8]
__device__ __forceinline__ void acc8m(u32x4 t, float m, float* A) {
  union { unsigned u; float f; } c;
  c.u = t[0] << 16;          A[0] = fmaf(m, c.f, A[0]);
  c.u = t[0] & 0xFFFF0000u;  A[1] = fmaf(m, c.f, A[1]);
  c.u = t[1] << 16;          A[2] = fmaf(m, c.f, A[2]);
  c.u = t[1] & 0xFFFF0000u;  A[3] = fmaf(m, c.f, A[3]);
  c.u = t[2] << 16;          A[4] = fmaf(m, c.f, A[4]);
  c.u = t[2] & 0xFFFF0000u;  A[5] = fmaf(m, c.f, A[5]);
  c.u = t[3] << 16;          A[6] = fmaf(m, c.f, A[6]);
  c.u = t[3] & 0xFFFF0000u;  A[7] = fmaf(m, c.f, A[7]);
}

__device__ __forceinline__ int lb_scalar(const int* __restrict__ a, int lo, int hi, int key) {
  while (lo < hi) {
    int mid = (lo + hi) >> 1;
    if (a[mid] < key) lo = mid + 1; else hi = mid;
  }
  return lo;
}

__device__ __forceinline__ int lb_fast_scalar(const int* __restrict__ a, int n, int key) {
  long long g = ((long long)key * (long long)n) >> 14;
  int L = (int)g - 3072, R = (int)g + 3072;
  if (L < 0) L = 0;
  if (R > n) R = n;
  const bool ok = (L == 0 || a[L - 1] < key) && (R == n || a[R] >= key);
  if (!ok) { L = 0; R = n; }
  return lb_scalar(a, L, R, key);
}

// wave-parallel lower_bound (fallback kernel only)
__device__ __forceinline__ int lb_wave(const int* __restrict__ a, int n, int key, int lane) {
  long long g = ((long long)key * (long long)n) >> 14;
  int L = (int)g - 3072, R = (int)g + 3072;
  if (L < 0) L = 0;
  if (R > n) R = n;
  const bool ok = (L == 0 || a[L - 1] < key) && (R == n || a[R] >= key);
  if (!ok) { L = 0; R = n; }
  int lo = L - 1, hi = R;
  while (hi - lo > 1) {
    const int width = hi - lo - 1;
    const int p = lo + 1 + (int)(((long long)width * lane) >> 6);
    const bool lt = a[p] < key;
    const unsigned long long m = __ballot(lt);
    const int t = m ? (63 - __builtin_clzll(m)) : -1;
    const int nlo = (t >= 0) ? lo + 1 + (int)(((long long)width * t) >> 6) : lo;
    const int nhi = (t < 63) ? lo + 1 + (int)(((long long)width * (t + 1)) >> 6) : hi;
    lo = nlo; hi = nhi;
  }
  return hi;
}

// ============== prep: scan boundaries + TW bf16 (16 rows/block) + W2 frags ==============
__global__ __launch_bounds__(256, 4) void prep_kernel(
    const int* __restrict__ diag_seg, const int* __restrict__ proc_seg,
    const int* __restrict__ med_seg,
    const float* __restrict__ dT, const float* __restrict__ pT, const float* __restrict__ mT,
    const float* __restrict__ W1, const float* __restrict__ W2,
    unsigned char* __restrict__ ws, int ND, int NP, int NM)
{
  __shared__ float w1L[128 * 64];   // 32 KB
  const int blk = blockIdx.x;
  const int tid = threadIdx.x;
  const int totSlots = ND + NP + NM + 3;
  const int SB = (totSlots + 255) >> 8;

  if (blk < SB) {
    // scan-based boundary fill: thread i of table T owns keys (seg[i-1], seg[i]]
    const int t = blk * 256 + tid;
    if (t < totSlots) {
      int T, i, n; const int* seg;
      if (t < ND + 1)           { T = 0; i = t;                 n = ND; seg = diag_seg; }
      else if (t < ND + NP + 2) { T = 1; i = t - (ND + 1);      n = NP; seg = proc_seg; }
      else                      { T = 2; i = t - (ND + NP + 2); n = NM; seg = med_seg; }
      const int prev = (i == 0) ? -1 : seg[i - 1];
      const int cur  = (i == n) ? NVIS : seg[i];
      int* o = (int*)(ws + OFFS_OFF) + T * OFFS_STRIDE;
      for (int k = prev + 1; k <= cur; ++k) o[k] = i;   // lower_bound(seg, k) == i
    }
  } else if (blk < SB + TWB_ALL) {
    const int blk2 = blk - SB;
    const float* tbl; int rows, r0, koff, tBase;
    if (blk2 < TWB_D)              { tbl = dT; rows = ROWS_D; r0 = blk2 * 16;           koff = 0;   tBase = TBASE_D; }
    else if (blk2 < TWB_D + TWB_P) { tbl = pT; rows = ROWS_P; r0 = (blk2 - TWB_D) * 16; koff = 128; tBase = TBASE_P; }
    else                           { tbl = mT; rows = ROWS_M; r0 = (blk2 - TWB_D - TWB_P) * 16; koff = 256; tBase = TBASE_M; }
    for (int i = tid; i < 128 * 64 / 4; i += 256)
      *(f32x4*)&w1L[i * 4] = *(const f32x4*)&W1[(size_t)koff * HID + i * 4];
    __syncthreads();
    const int j = tid & 63;
    #pragma unroll
    for (int rr = 0; rr < 4; ++rr) {
      const int r = r0 + rr * 4 + (tid >> 6);
      if (r < rows) {
        float acc = 0.f;
        #pragma unroll 8
        for (int k4 = 0; k4 < 32; ++k4) {
          const f32x4 t = *(const f32x4*)(tbl + (size_t)r * EMB + k4 * 4);
          acc += t[0] * w1L[(k4 * 4 + 0) * 64 + j] + t[1] * w1L[(k4 * 4 + 1) * 64 + j]
               + t[2] * w1L[(k4 * 4 + 2) * 64 + j] + t[3] * w1L[(k4 * 4 + 3) * 64 + j];
        }
        *(unsigned short*)(ws + TW_OFF + (size_t)(tBase + r) * 128 + j * 2) = f2bf(acc);
      }
    }
  } else {
    const int t = (blk - SB - TWB_ALL) * 256 + tid;
    if (t < NW2F) {
      const int lane = t & 63, tk = t >> 6;
      const int kh = tk & 1, tile = tk >> 1;
      const int n = tile * 16 + (lane & 15);
      const int k0 = kh * 32 + (lane >> 4) * 8;
      unsigned short e0[8];
      #pragma unroll
      for (int e = 0; e < 8; ++e)
        e0[e] = (n < MED) ? f2bf(W2[(size_t)(k0 + e) * MED + n]) : (unsigned short)0;
      u32x4 o;
      o[0] = (u32)e0[0] | ((u32)e0[1] << 16);
      o[1] = (u32)e0[2] | ((u32)e0[3] << 16);
      o[2] = (u32)e0[4] | ((u32)e0[5] << 16);
      o[3] = (u32)e0[6] | ((u32)e0[7] << 16);
      *(u32x4*)(ws + W2F_OFF + (size_t)t * 16) = o;
    }
  }
}

// ============== main: merged bf16-TW gather -> relu -> GEMM2 -> sigmoid (R7-proven) ==============
__global__ __launch_bounds__(NTHR, 8) void fused_ehr_v10(
    const int* __restrict__ diag_codes, const int* __restrict__ proc_codes,
    const int* __restrict__ med_codes,
    const float* __restrict__ b1, const float* __restrict__ b2,
    const unsigned char* __restrict__ ws,
    float* __restrict__ out)
{
  __shared__ __align__(16) unsigned short hs[VPB][HID + 8];  // 2304 B
  __shared__ int offsL[3][17];
  __shared__ int csL[17];
  __shared__ int twoffL[CAPT];                               // 6144 B

  const int tid = threadIdx.x;
  const int l = tid & 63;
  const int wv = tid >> 6;
  const int b0 = blockIdx.x * VPB;
  const int* offsAll = (const int*)(ws + OFFS_OFF);

  // ---- load precomputed boundaries (coalesced, 51 ints) ----
  if (tid < 51) {
    const int T = tid / 17, idx = tid - T * 17;
    offsL[T][idx] = offsAll[T * OFFS_STRIDE + b0 + idx];
  }
  __syncthreads();
  if (tid < 17) {
    csL[tid] = (offsL[0][tid] - offsL[0][0]) + (offsL[1][tid] - offsL[1][0])
             + (offsL[2][tid] - offsL[2][0]);
  }
  __syncthreads();

  const int total = csL[16];
  const bool stAll = (total <= CAPT);

  // ---- stage merged, visit-grouped TW byte-offsets ----
  if (stAll) {
#define STAGE(T, CG, TBASE)                                                     \
    {                                                                           \
      const int sT = offsL[T][0], cnt = offsL[T][16] - sT;                      \
      for (int i = tid; i < cnt; i += NTHR) {                                   \
        const int key = sT + i;                                                 \
        int lo = 0, hi = 16;                                                    \
        _Pragma("unroll")                                                       \
        for (int it = 0; it < 4; ++it) {                                        \
          const int m = (lo + hi) >> 1;                                         \
          if (offsL[T][m] <= key) lo = m; else hi = m;                          \
        }                                                                       \
        const int within = key - offsL[T][lo];                                  \
        int prior = 0;                                                          \
        if (T >= 1) prior += offsL[0][lo + 1] - offsL[0][lo];                   \
        if (T == 2) prior += offsL[1][lo + 1] - offsL[1][lo];                   \
        twoffL[csL[lo] + prior + within] = (TBASE + CG[key]) << 7;              \
      }                                                                         \
    }
    STAGE(0, diag_codes, TBASE_D)
    STAGE(1, proc_codes, TBASE_P)
    STAGE(2, med_codes,  TBASE_M)
#undef STAGE
  }
  __syncthreads();

  // ---- gather: one 32-lane half per visit; 128B bf16 TW rows, 8 lanes/row ----
  const int half = tid >> 5;        // visit 0..15
  const int ln = tid & 31;
  const int oct = ln >> 3;          // code slot 0..3
  const int sl = ln & 7;            // dim slice: dims sl*8 .. sl*8+7
  const unsigned char* twb = ws + TW_OFF;

  float A[8] = {0.f, 0.f, 0.f, 0.f, 0.f, 0.f, 0.f, 0.f};

  if (stAll) {
    const int s = csL[half], e = csL[half + 1];
    for (int jj = s; jj < e; jj += 16) {
      const int j0 = jj + oct, j1 = jj + 4 + oct, j2 = jj + 8 + oct, j3 = jj + 12 + oct;
      const int i0 = (j0 < e) ? j0 : (e - 1);
      const int i1 = (j1 < e) ? j1 : (e - 1);
      const int i2 = (j2 < e) ? j2 : (e - 1);
      const int i3 = (j3 < e) ? j3 : (e - 1);
      const u32x4 t0 = *(const u32x4*)(twb + twoffL[i0] + sl * 16);
      const u32x4 t1 = *(const u32x4*)(twb + twoffL[i1] + sl * 16);
      const u32x4 t2 = *(const u32x4*)(twb + twoffL[i2] + sl * 16);
      const u32x4 t3 = *(const u32x4*)(twb + twoffL[i3] + sl * 16);
      acc8m(t0, (j0 < e) ? 1.f : 0.f, A);
      acc8m(t1, (j1 < e) ? 1.f : 0.f, A);
      acc8m(t2, (j2 < e) ? 1.f : 0.f, A);
      acc8m(t3, (j3 < e) ? 1.f : 0.f, A);
    }
  } else {
    // rare fallback: per-table masked loops, codes from global
#define GFB(T, CG, TBASE)                                                       \
    {                                                                           \
      const int s = offsL[T][half], e = offsL[T][half + 1];                     \
      for (int jj = s; jj < e; jj += 8) {                                       \
        const int j0 = jj + oct, j1 = jj + 4 + oct;                             \
        const int i0 = (j0 < e) ? j0 : (e - 1);                                 \
        const int i1 = (j1 < e) ? j1 : (e - 1);                                 \
        const int o0 = (TBASE + CG[i0]) << 7;                                   \
        const int o1 = (TBASE + CG[i1]) << 7;                                   \
        const u32x4 t0 = *(const u32x4*)(twb + o0 + sl * 16);                   \
        const u32x4 t1 = *(const u32x4*)(twb + o1 + sl * 16);                   \
        acc8m(t0, (j0 < e) ? 1.f : 0.f, A);                                     \
        acc8m(t1, (j1 < e) ? 1.f : 0.f, A);                                     \
      }                                                                         \
    }
    GFB(0, diag_codes, TBASE_D)
    GFB(1, proc_codes, TBASE_P)
    GFB(2, med_codes,  TBASE_M)
#undef GFB
  }

  // reduce across the 4 code slots (octets)
  #pragma unroll
  for (int d = 0; d < 8; ++d) {
    A[d] += __shfl_xor(A[d], 8);
    A[d] += __shfl_xor(A[d], 16);
  }
  if (ln < 8) {
    const f32x4 bb0 = *(const f32x4*)(b1 + sl * 8);
    const f32x4 bb1 = *(const f32x4*)(b1 + sl * 8 + 4);
    u32x4 o;
    o[0] = (u32)f2bf(fmaxf(A[0] + bb0[0], 0.f)) | ((u32)f2bf(fmaxf(A[1] + bb0[1], 0.f)) << 16);
    o[1] = (u32)f2bf(fmaxf(A[2] + bb0[2], 0.f)) | ((u32)f2bf(fmaxf(A[3] + bb0[3], 0.f)) << 16);
    o[2] = (u32)f2bf(fmaxf(A[4] + bb1[0], 0.f)) | ((u32)f2bf(fmaxf(A[5] + bb1[1], 0.f)) << 16);
    o[3] = (u32)f2bf(fmaxf(A[6] + bb1[2], 0.f)) | ((u32)f2bf(fmaxf(A[7] + bb1[3], 0.f)) << 16);
    *(u32x4*)&hs[half][sl * 8] = o;
  }
  __syncthreads();

  // ---- GEMM2 (8 waves): out[16][153] = sigmoid(h @ W2 + b2); 10 N-tiles ----
  // A frag: row=l&15, k=(l>>4)*8+e.  B pre-swizzled.  D: col=l&15, row=(l>>4)*4+reg.
  const int jloc = l & 15;
  const int kq = l >> 4;
  const s16x8* w2f = (const s16x8*)(ws + W2F_OFF);

  for (int t = wv; t < 10; t += 8) {
    const int n = t * 16 + jloc;
    const bool nok = (n < MED);
    const s16x8 bw0 = w2f[(t * 2 + 0) * 64 + l];
    const s16x8 bw1 = w2f[(t * 2 + 1) * 64 + l];
    f32x4 o0 = {0.f, 0.f, 0.f, 0.f};
    {
      const int ko = kq * 8;
      const s16x8 a00 = *(const s16x8*)&hs[jloc][ko];
      o0 = __builtin_amdgcn_mfma_f32_16x16x32_bf16(a00, bw0, o0, 0, 0, 0);
      const s16x8 a01 = *(const s16x8*)&hs[jloc][ko + 32];
      o0 = __builtin_amdgcn_mfma_f32_16x16x32_bf16(a01, bw1, o0, 0, 0, 0);
    }
    if (nok) {
      const float bias2 = b2[n];
      #pragma unroll
      for (int r = 0; r < 4; ++r) {
        const int row = kq * 4 + r;
        const float z0 = o0[r] + bias2;
        out[(size_t)(b0 + row) * MED + n] = 1.f / (1.f + __expf(-z0));
      }
    }
  }
}

// ============== fallback (round-4 kernel, f32 tables, no ws) ==============
#define CAPD 640
#define CAPP 384
#define CAPM 512
#define CAPT_FB (CAPD + CAPP + CAPM)

__global__ __launch_bounds__(NTHR, 8) void fused_ehr_fb(
    const int* __restrict__ diag_codes, const int* __restrict__ diag_seg,
    const int* __restrict__ proc_codes, const int* __restrict__ proc_seg,
    const int* __restrict__ med_codes,  const int* __restrict__ med_seg,
    const float* __restrict__ diag_table, const float* __restrict__ proc_table,
    const float* __restrict__ med_table,
    const float* __restrict__ W1, const float* __restrict__ b1,
    const float* __restrict__ W2, const float* __restrict__ b2,
    float* __restrict__ out, int ND, int NP, int NM)
{
  __shared__ __align__(16) unsigned short xs[VPB][K1 + 8];
  __shared__ __align__(16) unsigned short hs[VPB][HID + 8];
  __shared__ int offs[3][VPB + 1];
  __shared__ int codesL[CAPT_FB];

  const int tid = threadIdx.x;
  const int l = tid & 63;
  const int wv = tid >> 6;
  const int b0 = blockIdx.x * VPB;

  if (wv < 6) {
    const int T = wv >> 1, w = wv & 1;
    const int* seg = (T == 0) ? diag_seg : (T == 1) ? proc_seg : med_seg;
    const int n = (T == 0) ? ND : (T == 1) ? NP : NM;
    const int r = lb_wave(seg, n, b0 + (w ? VPB : 0), l);
    if (l == 0) offs[T][w ? VPB : 0] = r;
  }
  __syncthreads();

  const int sD = offs[0][0], cntD = offs[0][VPB] - sD;
  const int sP = offs[1][0], cntP = offs[1][VPB] - sP;
  const int sM = offs[2][0], cntM = offs[2][VPB] - sM;
  const bool stD = (cntD <= CAPD), stP = (cntP <= CAPP), stM = (cntM <= CAPM);

  if (tid < 3 * (VPB - 1)) {
    const int T = tid / (VPB - 1), idx = tid - T * (VPB - 1) + 1;
    offs[T][idx] = offs[T][VPB];
  }
  if (stD) for (int i = tid; i < cntD; i += NTHR) codesL[i] = diag_codes[sD + i];
  if (stP) for (int i = tid; i < cntP; i += NTHR) codesL[CAPD + i] = proc_codes[sP + i];
  if (stM) for (int i = tid; i < cntM; i += NTHR) codesL[CAPD + CAPP + i] = med_codes[sM + i];
  __syncthreads();

#define MARK(Tidx, STAGED, CNT, SBASE, SEGG, NT)                                 \
  if (STAGED) {                                                                  \
    for (int i = tid; i < CNT; i += NTHR) {                                      \
      const int v1 = SEGG[SBASE + i];                                            \
      const int v0_ = (i == 0) ? (b0 - 1) : SEGG[SBASE + i - 1];                 \
      int klo = v0_ + 1; if (klo < b0 + 1) klo = b0 + 1;                         \
      int khi = v1;      if (khi > b0 + VPB - 1) khi = b0 + VPB - 1;             \
      for (int k = klo; k <= khi; ++k) offs[Tidx][k - b0] = SBASE + i;           \
    }                                                                            \
  } else if (tid < VPB - 1) {                                                    \
    offs[Tidx][tid + 1] = lb_fast_scalar(SEGG, NT, b0 + tid + 1);                \
  }

  MARK(0, stD, cntD, sD, diag_seg, ND)
  MARK(1, stP, cntP, sP, proc_seg, NP)
  MARK(2, stM, cntM, sM, med_seg,  NM)
#undef MARK
  __syncthreads();

  const int half = tid >> 5;
  const int ln = tid & 31;

#define GATH(T, CODES_G, TBL, STAGED, SGLOB, LBASE)                               \
  {                                                                               \
    const int s_ = offs[T][half], e_ = offs[T][half + 1];                         \
    float a0 = 0.f, a1 = 0.f, a2 = 0.f, a3 = 0.f;                                 \
    int i = s_;                                                                   \
    if (STAGED) {                                                                 \
      const int lb = LBASE - SGLOB;                                               \
      for (; i + 3 < e_; i += 4) {                                                \
        const int c0 = codesL[lb + i],     c1 = codesL[lb + i + 1];               \
        const int c2 = codesL[lb + i + 2], c3 = codesL[lb + i + 3];               \
        const f32x4 t0 = *(const f32x4*)(TBL + (size_t)c0 * EMB + ln * 4);        \
        const f32x4 t1 = *(const f32x4*)(TBL + (size_t)c1 * EMB + ln * 4);        \
        const f32x4 t2 = *(const f32x4*)(TBL + (size_t)c2 * EMB + ln * 4);        \
        const f32x4 t3 = *(const f32x4*)(TBL + (size_t)c3 * EMB + ln * 4);        \
        a0 += (t0[0] + t1[0]) + (t2[0] + t3[0]);                                  \
        a1 += (t0[1] + t1[1]) + (t2[1] + t3[1]);                                  \
        a2 += (t0[2] + t1[2]) + (t2[2] + t3[2]);                                  \
        a3 += (t0[3] + t1[3]) + (t2[3] + t3[3]);                                  \
      }                                                                           \
      for (; i < e_; ++i) {                                                       \
        const int c = codesL[lb + i];                                             \
        const f32x4 t = *(const f32x4*)(TBL + (size_t)c * EMB + ln * 4);          \
        a0 += t[0]; a1 += t[1]; a2 += t[2]; a3 += t[3];                           \
      }                                                                           \
    } else {                                                                      \
      for (; i < e_; ++i) {                                                       \
        const int c = CODES_G[i];                                                 \
        const f32x4 t = *(const f32x4*)(TBL + (size_t)c * EMB + ln * 4);          \
        a0 += t[0]; a1 += t[1]; a2 += t[2]; a3 += t[3];                           \
      }                                                                           \
    }                                                                             \
    const u32 p0 = (u32)f2bf(a0) | ((u32)f2bf(a1) << 16);                         \
    const u32 p1 = (u32)f2bf(a2) | ((u32)f2bf(a3) << 16);                         \
    uint2* d_ = (uint2*)&xs[half][T * EMB + ln * 4];                              \
    *d_ = make_uint2(p0, p1);                                                     \
  }

  GATH(0, diag_codes, diag_table, stD, sD, 0)
  GATH(1, proc_codes, proc_table, stP, sP, CAPD)
  GATH(2, med_codes,  med_table,  stM, sM, CAPD + CAPP)
#undef GATH
  __syncthreads();

  const int jloc = l & 15;
  const int kq = l >> 4;

  if (wv < 4) {
    const int j1 = wv * 16 + jloc;
    f32x4 acc = {0.f, 0.f, 0.f, 0.f};
    s16x8 bf;
    #pragma unroll
    for (int e = 0; e < 8; ++e)
      bf[e] = (short)f2bf(W1[(size_t)(kq * 8 + e) * HID + j1]);
    #pragma unroll
    for (int kt = 0; kt < 12; ++kt) {
      s16x8 nxt;
      if (kt < 11) {
        const int kb = (kt + 1) * 32 + kq * 8;
        #pragma unroll
        for (int e = 0; e < 8; ++e)
          nxt[e] = (short)f2bf(W1[(size_t)(kb + e) * HID + j1]);
      }
      const s16x8 a0 = *(const s16x8*)&xs[jloc][kt * 32 + kq * 8];
      acc = __builtin_amdgcn_mfma_f32_16x16x32_bf16(a0, bf, acc, 0, 0, 0);
      if (kt < 11) bf = nxt;
    }
    const float bias1 = b1[j1];
    #pragma unroll
    for (int r = 0; r < 4; ++r)
      hs[kq * 4 + r][j1] = f2bf(fmaxf(acc[r] + bias1, 0.f));
  }
  __syncthreads();

  for (int t = wv; t < 10; t += 8) {
    const int n = t * 16 + jloc;
    const bool nok = (n < MED);
    s16x8 bw0, bw1;
    #pragma unroll
    for (int e = 0; e < 8; ++e) {
      const int k0 = kq * 8 + e;
      bw0[e] = nok ? (short)f2bf(W2[(size_t)k0 * MED + n])        : (short)0;
      bw1[e] = nok ? (short)f2bf(W2[(size_t)(k0 + 32) * MED + n]) : (short)0;
    }
    f32x4 o0 = {0.f, 0.f, 0.f, 0.f};
    {
      const int ko = kq * 8;
      const s16x8 a00 = *(const s16x8*)&hs[jloc][ko];
      o0 = __builtin_amdgcn_mfma_f32_16x16x32_bf16(a00, bw0, o0, 0, 0, 0);
      const s16x8 a01 = *(const s16x8*)&hs[jloc][ko + 32];
      o0 = __builtin_amdgcn_mfma_f32_16x16x32_bf16(a01, bw1, o0, 0, 0, 0);
    }
    if (nok) {
      const float bias2 = b2[n];
      #pragma unroll
      for (int r = 0; r < 4; ++r) {
        const int row = kq * 4 + r;
        const float z0 = o0[r] + bias2;
        out[(size_t)(b0 + row) * MED + n] = 1.f / (1.f + __expf(-z0));
      }
    }
  }
}

extern "C" void kernel_launch(void* const* d_in, const int* in_sizes, int n_in,
                              void* d_out, int out_size, void* d_ws, size_t ws_size,
                              hipStream_t stream) {
  const int* diag_codes = (const int*)d_in[0];
  const int* diag_seg   = (const int*)d_in[1];
  const int* proc_codes = (const int*)d_in[2];
  const int* proc_seg   = (const int*)d_in[3];
  const int* med_codes  = (const int*)d_in[4];
  const int* med_seg    = (const int*)d_in[5];
  const float* diag_table = (const float*)d_in[6];
  const float* proc_table = (const float*)d_in[7];
  const float* med_table  = (const float*)d_in[8];
  const float* W1 = (const float*)d_in[9];
  const float* b1 = (const float*)d_in[10];
  const float* W2 = (const float*)d_in[11];
  const float* b2 = (const float*)d_in[12];
  float* out = (float*)d_out;

  const bool sizes_ok = (in_sizes[6] == ROWS_D * EMB) && (in_sizes[7] == ROWS_P * EMB)
                     && (in_sizes[8] == ROWS_M * EMB);
  if (ws_size >= WS_NEED && sizes_ok) {
    unsigned char* ws = (unsigned char*)d_ws;
    const int totSlots = in_sizes[0] + in_sizes[2] + in_sizes[4] + 3;
    const int SB = (totSlots + 255) >> 8;
    prep_kernel<<<dim3(SB + TWB_ALL + 5), dim3(256), 0, stream>>>(
        diag_seg, proc_seg, med_seg,
        diag_table, proc_table, med_table, W1, W2, ws,
        in_sizes[0], in_sizes[2], in_sizes[4]);
    fused_ehr_v10<<<dim3(NBLK), dim3(NTHR), 0, stream>>>(
        diag_codes, proc_codes, med_codes, b1, b2, ws, out);
  } else {
    fused_ehr_fb<<<dim3(NBLK), dim3(NTHR), 0, stream>>>(
        diag_codes, diag_seg, proc_codes, proc_seg, med_codes, med_seg,
        diag_table, proc_table, med_table, W1, b1, W2, b2, out,
        in_sizes[0], in_sizes[2], in_sizes[4]);
  }
}

// Round 11
// 25.623 us; speedup vs baseline: 1.2509x; 1.2509x over previous
//
#include <hip/hip_runtime.h>
#include <hip/hip_bf16.h>

#define NVIS 16384
#define EMB 128
#define HID 64
#define MED 153
#define K1 384
#define VPB 16
#define NTHR 512
#define NBLK (NVIS / VPB)    // 1024 blocks x 512 thr

// ---- d_ws layout (16B aligned) ----
#define W2F_OFF  0u                         // 10*2*64 frags * 16B = 20480
#define OFFS_OFF 20480u                     // 3 * 16388 * 4 = 196656
#define OFFS_STRIDE 16388
#define TW_OFF   (20480u + 196656u)         // 217136; 3653 rows * 128 B = 467584
#define WS_NEED  (217136u + 467584u)        // 684720

#define ROWS_D 2000
#define ROWS_P 1500
#define ROWS_M 153
#define TBASE_D 0
#define TBASE_P 2000
#define TBASE_M 3500

#define TWB_D 500            // 4 rows/block (R7-proven: keep phase parallelism high)
#define TWB_P 375
#define TWB_M 39
#define TWB_ALL (TWB_D + TWB_P + TWB_M)      // 914
#define NW2F 1280

typedef float f32x4 __attribute__((ext_vector_type(4)));
typedef short s16x8 __attribute__((ext_vector_type(8)));
typedef unsigned int u32;
typedef unsigned int u32x4 __attribute__((ext_vector_type(4)));

__device__ __forceinline__ unsigned short f2bf(float f) {
  union { float f; unsigned u; } v; v.f = f;
  unsigned r = v.u + 0x7FFFu + ((v.u >> 16) & 1u);   // round-to-nearest-even
  return (unsigned short)(r >> 16);
}

// unpack 8 bf16 from u32x4, masked-fma into A[8]
__device__ __forceinline__ void acc8m(u32x4 t, float m, float* A) {
  union { unsigned u; float f; } c;
  c.u = t[0] << 16;          A[0] = fmaf(m, c.f, A[0]);
  c.u = t[0] & 0xFFFF0000u;  A[1] = fmaf(m, c.f, A[1]);
  c.u = t[1] << 16;          A[2] = fmaf(m, c.f, A[2]);
  c.u = t[1] & 0xFFFF0000u;  A[3] = fmaf(m, c.f, A[3]);
  c.u = t[2] << 16;          A[4] = fmaf(m, c.f, A[4]);
  c.u = t[2] & 0xFFFF0000u;  A[5] = fmaf(m, c.f, A[5]);
  c.u = t[3] << 16;          A[6] = fmaf(m, c.f, A[6]);
  c.u = t[3] & 0xFFFF0000u;  A[7] = fmaf(m, c.f, A[7]);
}

__device__ __forceinline__ int lb_scalar(const int* __restrict__ a, int lo, int hi, int key) {
  while (lo < hi) {
    int mid = (lo + hi) >> 1;
    if (a[mid] < key) lo = mid + 1; else hi = mid;
  }
  return lo;
}

__device__ __forceinline__ int lb_fast_scalar(const int* __restrict__ a, int n, int key) {
  long long g = ((long long)key * (long long)n) >> 14;
  int L = (int)g - 3072, R = (int)g + 3072;
  if (L < 0) L = 0;
  if (R > n) R = n;
  const bool ok = (L == 0 || a[L - 1] < key) && (R == n || a[R] >= key);
  if (!ok) { L = 0; R = n; }
  return lb_scalar(a, L, R, key);
}

// wave-parallel lower_bound (fallback kernel only)
__device__ __forceinline__ int lb_wave(const int* __restrict__ a, int n, int key, int lane) {
  long long g = ((long long)key * (long long)n) >> 14;
  int L = (int)g - 3072, R = (int)g + 3072;
  if (L < 0) L = 0;
  if (R > n) R = n;
  const bool ok = (L == 0 || a[L - 1] < key) && (R == n || a[R] >= key);
  if (!ok) { L = 0; R = n; }
  int lo = L - 1, hi = R;
  while (hi - lo > 1) {
    const int width = hi - lo - 1;
    const int p = lo + 1 + (int)(((long long)width * lane) >> 6);
    const bool lt = a[p] < key;
    const unsigned long long m = __ballot(lt);
    const int t = m ? (63 - __builtin_clzll(m)) : -1;
    const int nlo = (t >= 0) ? lo + 1 + (int)(((long long)width * t) >> 6) : lo;
    const int nhi = (t < 63) ? lo + 1 + (int)(((long long)width * (t + 1)) >> 6) : hi;
    lo = nlo; hi = nhi;
  }
  return hi;
}

// ============== prep: scan boundaries + TW bf16 (4 rows/block) + W2 frags ==============
__global__ __launch_bounds__(256, 4) void prep_kernel(
    const int* __restrict__ diag_seg, const int* __restrict__ proc_seg,
    const int* __restrict__ med_seg,
    const float* __restrict__ dT, const float* __restrict__ pT, const float* __restrict__ mT,
    const float* __restrict__ W1, const float* __restrict__ W2,
    unsigned char* __restrict__ ws, int ND, int NP, int NM)
{
  __shared__ float w1L[128 * 64];   // 32 KB
  const int blk = blockIdx.x;
  const int tid = threadIdx.x;
  const int totSlots = ND + NP + NM + 3;
  const int SB = (totSlots + 255) >> 8;

  if (blk < SB) {
    // scan-based boundary fill: thread i of table T owns keys (seg[i-1], seg[i]]
    const int t = blk * 256 + tid;
    if (t < totSlots) {
      int T, i, n; const int* seg;
      if (t < ND + 1)           { T = 0; i = t;                 n = ND; seg = diag_seg; }
      else if (t < ND + NP + 2) { T = 1; i = t - (ND + 1);      n = NP; seg = proc_seg; }
      else                      { T = 2; i = t - (ND + NP + 2); n = NM; seg = med_seg; }
      const int prev = (i == 0) ? -1 : seg[i - 1];
      const int cur  = (i == n) ? NVIS : seg[i];
      int* o = (int*)(ws + OFFS_OFF) + T * OFFS_STRIDE;
      for (int k = prev + 1; k <= cur; ++k) o[k] = i;   // lower_bound(seg, k) == i
    }
  } else if (blk < SB + TWB_ALL) {
    const int blk2 = blk - SB;
    const float* tbl; int rows, r0, koff, tBase;
    if (blk2 < TWB_D)              { tbl = dT; rows = ROWS_D; r0 = blk2 * 4;           koff = 0;   tBase = TBASE_D; }
    else if (blk2 < TWB_D + TWB_P) { tbl = pT; rows = ROWS_P; r0 = (blk2 - TWB_D) * 4; koff = 128; tBase = TBASE_P; }
    else                           { tbl = mT; rows = ROWS_M; r0 = (blk2 - TWB_D - TWB_P) * 4; koff = 256; tBase = TBASE_M; }
    for (int i = tid; i < 128 * 64 / 4; i += 256)
      *(f32x4*)&w1L[i * 4] = *(const f32x4*)&W1[(size_t)koff * HID + i * 4];
    __syncthreads();
    const int r = r0 + (tid >> 6);
    const int j = tid & 63;
    if (r < rows) {
      float acc = 0.f;
      #pragma unroll 8
      for (int k4 = 0; k4 < 32; ++k4) {
        const f32x4 t = *(const f32x4*)(tbl + (size_t)r * EMB + k4 * 4);
        acc += t[0] * w1L[(k4 * 4 + 0) * 64 + j] + t[1] * w1L[(k4 * 4 + 1) * 64 + j]
             + t[2] * w1L[(k4 * 4 + 2) * 64 + j] + t[3] * w1L[(k4 * 4 + 3) * 64 + j];
      }
      *(unsigned short*)(ws + TW_OFF + (size_t)(tBase + r) * 128 + j * 2) = f2bf(acc);
    }
  } else {
    const int t = (blk - SB - TWB_ALL) * 256 + tid;
    if (t < NW2F) {
      const int lane = t & 63, tk = t >> 6;
      const int kh = tk & 1, tile = tk >> 1;
      const int n = tile * 16 + (lane & 15);
      const int k0 = kh * 32 + (lane >> 4) * 8;
      unsigned short e0[8];
      #pragma unroll
      for (int e = 0; e < 8; ++e)
        e0[e] = (n < MED) ? f2bf(W2[(size_t)(k0 + e) * MED + n]) : (unsigned short)0;
      u32x4 o;
      o[0] = (u32)e0[0] | ((u32)e0[1] << 16);
      o[1] = (u32)e0[2] | ((u32)e0[3] << 16);
      o[2] = (u32)e0[4] | ((u32)e0[5] << 16);
      o[3] = (u32)e0[6] | ((u32)e0[7] << 16);
      *(u32x4*)(ws + W2F_OFF + (size_t)t * 16) = o;
    }
  }
}

// ============== main v11: stage-free gather -> relu -> GEMM2 -> sigmoid ==============
// Per 32-lane half (one visit): 6 broadcast boundary loads, 3 masked gather loops
// with codes direct from global (broadcast within 8-lane row groups). ONE barrier.
__global__ __launch_bounds__(NTHR, 8) void fused_ehr_v11(
    const int* __restrict__ diag_codes, const int* __restrict__ proc_codes,
    const int* __restrict__ med_codes,
    const float* __restrict__ b1, const float* __restrict__ b2,
    const unsigned char* __restrict__ ws,
    float* __restrict__ out)
{
  __shared__ __align__(16) unsigned short hs[VPB][HID + 8];  // 2304 B

  const int tid = threadIdx.x;
  const int l = tid & 63;
  const int wv = tid >> 6;
  const int b0 = blockIdx.x * VPB;
  const int* offsAll = (const int*)(ws + OFFS_OFF);

  const int half = tid >> 5;        // visit 0..15
  const int ln = tid & 31;
  const int oct = ln >> 3;          // code slot 0..3
  const int sl = ln & 7;            // dim slice: dims sl*8 .. sl*8+7
  const unsigned char* twb = ws + TW_OFF;

  // 6 independent broadcast boundary loads (no LDS, no sync)
  const int sD = offsAll[b0 + half];
  const int eD = offsAll[b0 + half + 1];
  const int sP = offsAll[OFFS_STRIDE + b0 + half];
  const int eP = offsAll[OFFS_STRIDE + b0 + half + 1];
  const int sM = offsAll[2 * OFFS_STRIDE + b0 + half];
  const int eM = offsAll[2 * OFFS_STRIDE + b0 + half + 1];

  float A[8] = {0.f, 0.f, 0.f, 0.f, 0.f, 0.f, 0.f, 0.f};

  // diag: stride 16 (4 slots x 4-deep)
  for (int jj = sD; jj < eD; jj += 16) {
    const int j0 = jj + oct, j1 = jj + 4 + oct, j2 = jj + 8 + oct, j3 = jj + 12 + oct;
    const int i0 = (j0 < eD) ? j0 : (eD - 1);
    const int i1 = (j1 < eD) ? j1 : (eD - 1);
    const int i2 = (j2 < eD) ? j2 : (eD - 1);
    const int i3 = (j3 < eD) ? j3 : (eD - 1);
    const int c0 = diag_codes[i0], c1 = diag_codes[i1];
    const int c2 = diag_codes[i2], c3 = diag_codes[i3];
    const u32x4 t0 = *(const u32x4*)(twb + ((size_t)(TBASE_D + c0) << 7) + (sl << 4));
    const u32x4 t1 = *(const u32x4*)(twb + ((size_t)(TBASE_D + c1) << 7) + (sl << 4));
    const u32x4 t2 = *(const u32x4*)(twb + ((size_t)(TBASE_D + c2) << 7) + (sl << 4));
    const u32x4 t3 = *(const u32x4*)(twb + ((size_t)(TBASE_D + c3) << 7) + (sl << 4));
    acc8m(t0, (j0 < eD) ? 1.f : 0.f, A);
    acc8m(t1, (j1 < eD) ? 1.f : 0.f, A);
    acc8m(t2, (j2 < eD) ? 1.f : 0.f, A);
    acc8m(t3, (j3 < eD) ? 1.f : 0.f, A);
  }
  // proc: stride 8 (4 slots x 2-deep)
  for (int jj = sP; jj < eP; jj += 8) {
    const int j0 = jj + oct, j1 = jj + 4 + oct;
    const int i0 = (j0 < eP) ? j0 : (eP - 1);
    const int i1 = (j1 < eP) ? j1 : (eP - 1);
    const int c0 = proc_codes[i0], c1 = proc_codes[i1];
    const u32x4 t0 = *(const u32x4*)(twb + ((size_t)(TBASE_P + c0) << 7) + (sl << 4));
    const u32x4 t1 = *(const u32x4*)(twb + ((size_t)(TBASE_P + c1) << 7) + (sl << 4));
    acc8m(t0, (j0 < eP) ? 1.f : 0.f, A);
    acc8m(t1, (j1 < eP) ? 1.f : 0.f, A);
  }
  // med: stride 8 (4 slots x 2-deep)
  for (int jj = sM; jj < eM; jj += 8) {
    const int j0 = jj + oct, j1 = jj + 4 + oct;
    const int i0 = (j0 < eM) ? j0 : (eM - 1);
    const int i1 = (j1 < eM) ? j1 : (eM - 1);
    const int c0 = med_codes[i0], c1 = med_codes[i1];
    const u32x4 t0 = *(const u32x4*)(twb + ((size_t)(TBASE_M + c0) << 7) + (sl << 4));
    const u32x4 t1 = *(const u32x4*)(twb + ((size_t)(TBASE_M + c1) << 7) + (sl << 4));
    acc8m(t0, (j0 < eM) ? 1.f : 0.f, A);
    acc8m(t1, (j1 < eM) ? 1.f : 0.f, A);
  }

  // reduce across the 4 code slots (xor 8/16 stays within the 32-lane half)
  #pragma unroll
  for (int d = 0; d < 8; ++d) {
    A[d] += __shfl_xor(A[d], 8);
    A[d] += __shfl_xor(A[d], 16);
  }
  if (ln < 8) {
    const f32x4 bb0 = *(const f32x4*)(b1 + sl * 8);
    const f32x4 bb1 = *(const f32x4*)(b1 + sl * 8 + 4);
    u32x4 o;
    o[0] = (u32)f2bf(fmaxf(A[0] + bb0[0], 0.f)) | ((u32)f2bf(fmaxf(A[1] + bb0[1], 0.f)) << 16);
    o[1] = (u32)f2bf(fmaxf(A[2] + bb0[2], 0.f)) | ((u32)f2bf(fmaxf(A[3] + bb0[3], 0.f)) << 16);
    o[2] = (u32)f2bf(fmaxf(A[4] + bb1[0], 0.f)) | ((u32)f2bf(fmaxf(A[5] + bb1[1], 0.f)) << 16);
    o[3] = (u32)f2bf(fmaxf(A[6] + bb1[2], 0.f)) | ((u32)f2bf(fmaxf(A[7] + bb1[3], 0.f)) << 16);
    *(u32x4*)&hs[half][sl * 8] = o;
  }
  __syncthreads();   // the ONE barrier

  // ---- GEMM2 (8 waves): out[16][153] = sigmoid(h @ W2 + b2); 10 N-tiles ----
  // A frag: row=l&15, k=(l>>4)*8+e.  B pre-swizzled.  D: col=l&15, row=(l>>4)*4+reg.
  const int jloc = l & 15;
  const int kq = l >> 4;
  const s16x8* w2f = (const s16x8*)(ws + W2F_OFF);

  for (int t = wv; t < 10; t += 8) {
    const int n = t * 16 + jloc;
    const bool nok = (n < MED);
    const s16x8 bw0 = w2f[(t * 2 + 0) * 64 + l];
    const s16x8 bw1 = w2f[(t * 2 + 1) * 64 + l];
    f32x4 o0 = {0.f, 0.f, 0.f, 0.f};
    {
      const int ko = kq * 8;
      const s16x8 a00 = *(const s16x8*)&hs[jloc][ko];
      o0 = __builtin_amdgcn_mfma_f32_16x16x32_bf16(a00, bw0, o0, 0, 0, 0);
      const s16x8 a01 = *(const s16x8*)&hs[jloc][ko + 32];
      o0 = __builtin_amdgcn_mfma_f32_16x16x32_bf16(a01, bw1, o0, 0, 0, 0);
    }
    if (nok) {
      const float bias2 = b2[n];
      #pragma unroll
      for (int r = 0; r < 4; ++r) {
        const int row = kq * 4 + r;
        const float z0 = o0[r] + bias2;
        out[(size_t)(b0 + row) * MED + n] = 1.f / (1.f + __expf(-z0));
      }
    }
  }
}

// ============== fallback (round-4 kernel, f32 tables, no ws) ==============
#define CAPD 640
#define CAPP 384
#define CAPM 512
#define CAPT_FB (CAPD + CAPP + CAPM)

__global__ __launch_bounds__(NTHR, 8) void fused_ehr_fb(
    const int* __restrict__ diag_codes, const int* __restrict__ diag_seg,
    const int* __restrict__ proc_codes, const int* __restrict__ proc_seg,
    const int* __restrict__ med_codes,  const int* __restrict__ med_seg,
    const float* __restrict__ diag_table, const float* __restrict__ proc_table,
    const float* __restrict__ med_table,
    const float* __restrict__ W1, const float* __restrict__ b1,
    const float* __restrict__ W2, const float* __restrict__ b2,
    float* __restrict__ out, int ND, int NP, int NM)
{
  __shared__ __align__(16) unsigned short xs[VPB][K1 + 8];
  __shared__ __align__(16) unsigned short hs[VPB][HID + 8];
  __shared__ int offs[3][VPB + 1];
  __shared__ int codesL[CAPT_FB];

  const int tid = threadIdx.x;
  const int l = tid & 63;
  const int wv = tid >> 6;
  const int b0 = blockIdx.x * VPB;

  if (wv < 6) {
    const int T = wv >> 1, w = wv & 1;
    const int* seg = (T == 0) ? diag_seg : (T == 1) ? proc_seg : med_seg;
    const int n = (T == 0) ? ND : (T == 1) ? NP : NM;
    const int r = lb_wave(seg, n, b0 + (w ? VPB : 0), l);
    if (l == 0) offs[T][w ? VPB : 0] = r;
  }
  __syncthreads();

  const int sD = offs[0][0], cntD = offs[0][VPB] - sD;
  const int sP = offs[1][0], cntP = offs[1][VPB] - sP;
  const int sM = offs[2][0], cntM = offs[2][VPB] - sM;
  const bool stD = (cntD <= CAPD), stP = (cntP <= CAPP), stM = (cntM <= CAPM);

  if (tid < 3 * (VPB - 1)) {
    const int T = tid / (VPB - 1), idx = tid - T * (VPB - 1) + 1;
    offs[T][idx] = offs[T][VPB];
  }
  if (stD) for (int i = tid; i < cntD; i += NTHR) codesL[i] = diag_codes[sD + i];
  if (stP) for (int i = tid; i < cntP; i += NTHR) codesL[CAPD + i] = proc_codes[sP + i];
  if (stM) for (int i = tid; i < cntM; i += NTHR) codesL[CAPD + CAPP + i] = med_codes[sM + i];
  __syncthreads();

#define MARK(Tidx, STAGED, CNT, SBASE, SEGG, NT)                                 \
  if (STAGED) {                                                                  \
    for (int i = tid; i < CNT; i += NTHR) {                                      \
      const int v1 = SEGG[SBASE + i];                                            \
      const int v0_ = (i == 0) ? (b0 - 1) : SEGG[SBASE + i - 1];                 \
      int klo = v0_ + 1; if (klo < b0 + 1) klo = b0 + 1;                         \
      int khi = v1;      if (khi > b0 + VPB - 1) khi = b0 + VPB - 1;             \
      for (int k = klo; k <= khi; ++k) offs[Tidx][k - b0] = SBASE + i;           \
    }                                                                            \
  } else if (tid < VPB - 1) {                                                    \
    offs[Tidx][tid + 1] = lb_fast_scalar(SEGG, NT, b0 + tid + 1);                \
  }

  MARK(0, stD, cntD, sD, diag_seg, ND)
  MARK(1, stP, cntP, sP, proc_seg, NP)
  MARK(2, stM, cntM, sM, med_seg,  NM)
#undef MARK
  __syncthreads();

  const int half = tid >> 5;
  const int ln = tid & 31;

#define GATH(T, CODES_G, TBL, STAGED, SGLOB, LBASE)                               \
  {                                                                               \
    const int s_ = offs[T][half], e_ = offs[T][half + 1];                         \
    float a0 = 0.f, a1 = 0.f, a2 = 0.f, a3 = 0.f;                                 \
    int i = s_;                                                                   \
    if (STAGED) {                                                                 \
      const int lb = LBASE - SGLOB;                                               \
      for (; i + 3 < e_; i += 4) {                                                \
        const int c0 = codesL[lb + i],     c1 = codesL[lb + i + 1];               \
        const int c2 = codesL[lb + i + 2], c3 = codesL[lb + i + 3];               \
        const f32x4 t0 = *(const f32x4*)(TBL + (size_t)c0 * EMB + ln * 4);        \
        const f32x4 t1 = *(const f32x4*)(TBL + (size_t)c1 * EMB + ln * 4);        \
        const f32x4 t2 = *(const f32x4*)(TBL + (size_t)c2 * EMB + ln * 4);        \
        const f32x4 t3 = *(const f32x4*)(TBL + (size_t)c3 * EMB + ln * 4);        \
        a0 += (t0[0] + t1[0]) + (t2[0] + t3[0]);                                  \
        a1 += (t0[1] + t1[1]) + (t2[1] + t3[1]);                                  \
        a2 += (t0[2] + t1[2]) + (t2[2] + t3[2]);                                  \
        a3 += (t0[3] + t1[3]) + (t2[3] + t3[3]);                                  \
      }                                                                           \
      for (; i < e_; ++i) {                                                       \
        const int c = codesL[lb + i];                                             \
        const f32x4 t = *(const f32x4*)(TBL + (size_t)c * EMB + ln * 4);          \
        a0 += t[0]; a1 += t[1]; a2 += t[2]; a3 += t[3];                           \
      }                                                                           \
    } else {                                                                      \
      for (; i < e_; ++i) {                                                       \
        const int c = CODES_G[i];                                                 \
        const f32x4 t = *(const f32x4*)(TBL + (size_t)c * EMB + ln * 4);          \
        a0 += t[0]; a1 += t[1]; a2 += t[2]; a3 += t[3];                           \
      }                                                                           \
    }                                                                             \
    const u32 p0 = (u32)f2bf(a0) | ((u32)f2bf(a1) << 16);                         \
    const u32 p1 = (u32)f2bf(a2) | ((u32)f2bf(a3) << 16);                         \
    uint2* d_ = (uint2*)&xs[half][T * EMB + ln * 4];                              \
    *d_ = make_uint2(p0, p1);                                                     \
  }

  GATH(0, diag_codes, diag_table, stD, sD, 0)
  GATH(1, proc_codes, proc_table, stP, sP, CAPD)
  GATH(2, med_codes,  med_table,  stM, sM, CAPD + CAPP)
#undef GATH
  __syncthreads();

  const int jloc = l & 15;
  const int kq = l >> 4;

  if (wv < 4) {
    const int j1 = wv * 16 + jloc;
    f32x4 acc = {0.f, 0.f, 0.f, 0.f};
    s16x8 bf;
    #pragma unroll
    for (int e = 0; e < 8; ++e)
      bf[e] = (short)f2bf(W1[(size_t)(kq * 8 + e) * HID + j1]);
    #pragma unroll
    for (int kt = 0; kt < 12; ++kt) {
      s16x8 nxt;
      if (kt < 11) {
        const int kb = (kt + 1) * 32 + kq * 8;
        #pragma unroll
        for (int e = 0; e < 8; ++e)
          nxt[e] = (short)f2bf(W1[(size_t)(kb + e) * HID + j1]);
      }
      const s16x8 a0 = *(const s16x8*)&xs[jloc][kt * 32 + kq * 8];
      acc = __builtin_amdgcn_mfma_f32_16x16x32_bf16(a0, bf, acc, 0, 0, 0);
      if (kt < 11) bf = nxt;
    }
    const float bias1 = b1[j1];
    #pragma unroll
    for (int r = 0; r < 4; ++r)
      hs[kq * 4 + r][j1] = f2bf(fmaxf(acc[r] + bias1, 0.f));
  }
  __syncthreads();

  for (int t = wv; t < 10; t += 8) {
    const int n = t * 16 + jloc;
    const bool nok = (n < MED);
    s16x8 bw0, bw1;
    #pragma unroll
    for (int e = 0; e < 8; ++e) {
      const int k0 = kq * 8 + e;
      bw0[e] = nok ? (short)f2bf(W2[(size_t)k0 * MED + n])        : (short)0;
      bw1[e] = nok ? (short)f2bf(W2[(size_t)(k0 + 32) * MED + n]) : (short)0;
    }
    f32x4 o0 = {0.f, 0.f, 0.f, 0.f};
    {
      const int ko = kq * 8;
      const s16x8 a00 = *(const s16x8*)&hs[jloc][ko];
      o0 = __builtin_amdgcn_mfma_f32_16x16x32_bf16(a00, bw0, o0, 0, 0, 0);
      const s16x8 a01 = *(const s16x8*)&hs[jloc][ko + 32];
      o0 = __builtin_amdgcn_mfma_f32_16x16x32_bf16(a01, bw1, o0, 0, 0, 0);
    }
    if (nok) {
      const float bias2 = b2[n];
      #pragma unroll
      for (int r = 0; r < 4; ++r) {
        const int row = kq * 4 + r;
        const float z0 = o0[r] + bias2;
        out[(size_t)(b0 + row) * MED + n] = 1.f / (1.f + __expf(-z0));
      }
    }
  }
}

extern "C" void kernel_launch(void* const* d_in, const int* in_sizes, int n_in,
                              void* d_out, int out_size, void* d_ws, size_t ws_size,
                              hipStream_t stream) {
  const int* diag_codes = (const int*)d_in[0];
  const int* diag_seg   = (const int*)d_in[1];
  const int* proc_codes = (const int*)d_in[2];
  const int* proc_seg   = (const int*)d_in[3];
  const int* med_codes  = (const int*)d_in[4];
  const int* med_seg    = (const int*)d_in[5];
  const float* diag_table = (const float*)d_in[6];
  const float* proc_table = (const float*)d_in[7];
  const float* med_table  = (const float*)d_in[8];
  const float* W1 = (const float*)d_in[9];
  const float* b1 = (const float*)d_in[10];
  const float* W2 = (const float*)d_in[11];
  const float* b2 = (const float*)d_in[12];
  float* out = (float*)d_out;

  const bool sizes_ok = (in_sizes[6] == ROWS_D * EMB) && (in_sizes[7] == ROWS_P * EMB)
                     && (in_sizes[8] == ROWS_M * EMB);
  if (ws_size >= WS_NEED && sizes_ok) {
    unsigned char* ws = (unsigned char*)d_ws;
    const int totSlots = in_sizes[0] + in_sizes[2] + in_sizes[4] + 3;
    const int SB = (totSlots + 255) >> 8;
    prep_kernel<<<dim3(SB + TWB_ALL + 5), dim3(256), 0, stream>>>(
        diag_seg, proc_seg, med_seg,
        diag_table, proc_table, med_table, W1, W2, ws,
        in_sizes[0], in_sizes[2], in_sizes[4]);
    fused_ehr_v11<<<dim3(NBLK), dim3(NTHR), 0, stream>>>(
        diag_codes, proc_codes, med_codes, b1, b2, ws, out);
  } else {
    fused_ehr_fb<<<dim3(NBLK), dim3(NTHR), 0, stream>>>(
        diag_codes, diag_seg, proc_codes, proc_seg, med_codes, med_seg,
        diag_table, proc_table, med_table, W1, b1, W2, b2, out,
        in_sizes[0], in_sizes[2], in_sizes[4]);
  }
}